// Round 8
// baseline (389.232 us; speedup 1.0000x reference)
//
#include <hip/hip_runtime.h>
#include <math.h>

// RansacRouting: B=32, I=1152, O=10, D=16, H=10, S=922
// Round 8: DIAGNOSTIC. Three different structures all pinned at 43-46us
// (R1 gather / R4 scan / R7 mask-hoist) -> hypothesis-driven rewrites are
// failing; ablate empirically. Real kernel = verified R4 (correct output).
// Appended ablation dispatches (ws-only writes, 8x grid so they rank above
// the 44us fill dispatches in top-5):
//   abl_stage   x8: loads+scatter+vn only     -> memory phase cost
//   abl_compute x8: fabricated inputs, scan+Mu+loss+argmin -> VALU cost
//   abl_skel    x8: DPP/LDS/barrier skeleton, trivial bodies -> sync cost
// Readout: visible => phase = dur/8; missing => phase < ~5.5us per-320.

#define B_    32
#define I_    1152
#define O_    10
#define D_    16
#define H_    10
#define S_    922
#define MASKW 36      // 1152/32
#define NT    384
#define NW    6       // waves per block
#define RPT   3       // rows per thread: 1152/384
#define HH    11      // 10 hypotheses + 1 "all rows" (tot)
#define ABLG  (8 * B_ * O_)   // 2560 ablation blocks

// ---- wave64 sum via DPP (VALU pipe, no LDS) -- result valid in lane 63 ----
template <int CTRL, int ROWM>
static __device__ __forceinline__ float dpp_f(float v) {
    return __int_as_float(__builtin_amdgcn_update_dpp(
        0, __float_as_int(v), CTRL, ROWM, 0xf, true));
}
static __device__ __forceinline__ float wave_sum_f32(float v) {
    v += dpp_f<0x111, 0xf>(v);   // row_shr:1
    v += dpp_f<0x112, 0xf>(v);   // row_shr:2
    v += dpp_f<0x114, 0xf>(v);   // row_shr:4
    v += dpp_f<0x118, 0xf>(v);   // row_shr:8
    v += dpp_f<0x142, 0xa>(v);   // row_bcast15 -> rows 1,3
    v += dpp_f<0x143, 0xc>(v);   // row_bcast31 -> rows 2,3
    return v;                    // lane 63 holds the total
}
template <int CTRL, int ROWM>
static __device__ __forceinline__ double dpp_d(double v) {
    long long x = __double_as_longlong(v);
    int lo = (int)(unsigned)(x & 0xffffffffLL);
    int hi = (int)(x >> 32);
    lo = __builtin_amdgcn_update_dpp(0, lo, CTRL, ROWM, 0xf, true);
    hi = __builtin_amdgcn_update_dpp(0, hi, CTRL, ROWM, 0xf, true);
    return __longlong_as_double((long long)(unsigned)lo | ((long long)hi << 32));
}
static __device__ __forceinline__ double wave_sum_f64(double v) {
    v += dpp_d<0x111, 0xf>(v);
    v += dpp_d<0x112, 0xf>(v);
    v += dpp_d<0x114, 0xf>(v);
    v += dpp_d<0x118, 0xf>(v);
    v += dpp_d<0x142, 0xa>(v);
    v += dpp_d<0x143, 0xc>(v);
    return v;
}

static __device__ __forceinline__ void task_bo(int p, int& b, int& o) {
    int xcd = p & 7, g = p >> 3;
    int gg = g / O_;
    b = xcd + 8 * gg;
    o = g - O_ * gg;
}

// ================= REAL KERNEL (verified R4, unchanged) ===================
__global__ __launch_bounds__(NT, 3) void ransac_kernel(
    const float* __restrict__ up,      // [B,I,O,D]
    const int*   __restrict__ sidx,    // [B,S,O,H]
    float*       __restrict__ out)     // [B,O,D]
{
    __shared__ unsigned                 mask[H_][MASKW];
    __shared__ __align__(16) float      hred[HH][NW][20];
    __shared__ float                    Mu_s[H_][D_];
    __shared__ double                   lpart[H_][NW];
    __shared__ double                   losses[H_];
    __shared__ int                      hstar;

    const int blk = blockIdx.x;
    int b, o; task_bo(blk, b, o);
    const int bo  = b * O_ + o;

    const int tid  = threadIdx.x;
    const int lane = tid & 63;
    const int wv   = tid >> 6;

    if (tid < H_ * MASKW) ((unsigned*)mask)[tid] = 0u;
    __syncthreads();

    const int* sb = sidx + (size_t)b * (S_ * O_ * H_) + o * H_;
    const bool p2 = tid < (S_ - 2 * NT);
    const int2* ps0 = (const int2*)(sb + (size_t)tid * (O_ * H_));
    const int2* ps1 = (const int2*)(sb + (size_t)(tid + NT) * (O_ * H_));
    int2 a0 = ps0[0], a1 = ps0[1], a2 = ps0[2], a3 = ps0[3], a4 = ps0[4];
    int2 b0 = ps1[0], b1 = ps1[1], b2 = ps1[2], b3 = ps1[3], b4 = ps1[4];
    int2 c0 = {0,0}, c1 = {0,0}, c2 = {0,0}, c3 = {0,0}, c4 = {0,0};
    if (p2) {
        const int2* ps2 = (const int2*)(sb + (size_t)(tid + 2 * NT) * (O_ * H_));
        c0 = ps2[0]; c1 = ps2[1]; c2 = ps2[2]; c3 = ps2[3]; c4 = ps2[4];
    }

    const float* ub = up + ((size_t)b * I_ * O_ + o) * D_;
    float4 R[RPT][4];
    #pragma unroll
    for (int r = 0; r < RPT; ++r) {
        const float4* p = (const float4*)(ub + (size_t)(tid + r * NT) * (O_ * D_));
        R[r][0] = p[0]; R[r][1] = p[1]; R[r][2] = p[2]; R[r][3] = p[3];
    }

    {
        int v0[H_] = {a0.x, a0.y, a1.x, a1.y, a2.x, a2.y, a3.x, a3.y, a4.x, a4.y};
        #pragma unroll
        for (int h = 0; h < H_; ++h)
            atomicOr(&mask[h][v0[h] >> 5], 1u << (v0[h] & 31));
        int v1[H_] = {b0.x, b0.y, b1.x, b1.y, b2.x, b2.y, b3.x, b3.y, b4.x, b4.y};
        #pragma unroll
        for (int h = 0; h < H_; ++h)
            atomicOr(&mask[h][v1[h] >> 5], 1u << (v1[h] & 31));
        if (p2) {
            int v2[H_] = {c0.x, c0.y, c1.x, c1.y, c2.x, c2.y, c3.x, c3.y, c4.x, c4.y};
            #pragma unroll
            for (int h = 0; h < H_; ++h)
                atomicOr(&mask[h][v2[h] >> 5], 1u << (v2[h] & 31));
        }
    }

    float vn[RPT], usq[RPT];
    #pragma unroll
    for (int r = 0; r < RPT; ++r) {
        float4 q0 = R[r][0], q1 = R[r][1], q2 = R[r][2], q3 = R[r][3];
        float s = q0.x*q0.x + q0.y*q0.y + q0.z*q0.z + q0.w*q0.w
                + q1.x*q1.x + q1.y*q1.y + q1.z*q1.z + q1.w*q1.w
                + q2.x*q2.x + q2.y*q2.y + q2.z*q2.z + q2.w*q2.w
                + q3.x*q3.x + q3.y*q3.y + q3.z*q3.z + q3.w*q3.w;
        vn[r] = sqrtf(s);
        float uq[D_] = {q0.x,q0.y,q0.z,q0.w, q1.x,q1.y,q1.z,q1.w,
                        q2.x,q2.y,q2.z,q2.w, q3.x,q3.y,q3.z,q3.w};
        float t = 0.f;
        #pragma unroll
        for (int d = 0; d < D_; ++d) t = fmaf(uq[d], uq[d], t);
        usq[r] = t;
    }
    __syncthreads();

    const int      w0   = tid >> 5;
    const unsigned bitm = 1u << (tid & 31);
    for (int h = 0; h < HH; ++h) {
        float na[17];
        #pragma unroll
        for (int d = 0; d < 17; ++d) na[d] = 0.f;
        #pragma unroll
        for (int r = 0; r < RPT; ++r) {
            float w = vn[r];
            if (h < H_) {
                unsigned mw = mask[h][w0 + 12 * r];
                w = (mw & bitm) ? 0.f : w;
            }
            float4 q0 = R[r][0], q1 = R[r][1], q2 = R[r][2], q3 = R[r][3];
            na[ 0] = fmaf(w, q0.x, na[ 0]); na[ 1] = fmaf(w, q0.y, na[ 1]);
            na[ 2] = fmaf(w, q0.z, na[ 2]); na[ 3] = fmaf(w, q0.w, na[ 3]);
            na[ 4] = fmaf(w, q1.x, na[ 4]); na[ 5] = fmaf(w, q1.y, na[ 5]);
            na[ 6] = fmaf(w, q1.z, na[ 6]); na[ 7] = fmaf(w, q1.w, na[ 7]);
            na[ 8] = fmaf(w, q2.x, na[ 8]); na[ 9] = fmaf(w, q2.y, na[ 9]);
            na[10] = fmaf(w, q2.z, na[10]); na[11] = fmaf(w, q2.w, na[11]);
            na[12] = fmaf(w, q3.x, na[12]); na[13] = fmaf(w, q3.y, na[13]);
            na[14] = fmaf(w, q3.z, na[14]); na[15] = fmaf(w, q3.w, na[15]);
            na[16] += w;
        }
        #pragma unroll
        for (int d = 0; d < 17; ++d) na[d] = wave_sum_f32(na[d]);
        if (lane == 63) {
            *(float4*)&hred[h][wv][ 0] = make_float4(na[ 0], na[ 1], na[ 2], na[ 3]);
            *(float4*)&hred[h][wv][ 4] = make_float4(na[ 4], na[ 5], na[ 6], na[ 7]);
            *(float4*)&hred[h][wv][ 8] = make_float4(na[ 8], na[ 9], na[10], na[11]);
            *(float4*)&hred[h][wv][12] = make_float4(na[12], na[13], na[14], na[15]);
            hred[h][wv][16] = na[16];
        }
    }
    __syncthreads();

    for (int h = wv; h < H_; h += NW) {
        if (lane < D_) {
            float naj = 0.f, totj = 0.f, na16 = 0.f, tot16 = 0.f;
            #pragma unroll
            for (int w = 0; w < NW; ++w) {
                naj   += hred[h ][w][lane];
                totj  += hred[10][w][lane];
                na16  += hred[h ][w][16];
                tot16 += hred[10][w][16];
            }
            float rd = 1.f / (tot16 - na16);
            Mu_s[h][lane] = (totj - naj) * rd;
        }
    }
    __syncthreads();

    for (int h = 0; h < H_; ++h) {
        float4 m0 = *(const float4*)&Mu_s[h][0];
        float4 m1 = *(const float4*)&Mu_s[h][4];
        float4 m2 = *(const float4*)&Mu_s[h][8];
        float4 m3 = *(const float4*)&Mu_s[h][12];
        float mv[D_] = {m0.x, m0.y, m0.z, m0.w, m1.x, m1.y, m1.z, m1.w,
                        m2.x, m2.y, m2.z, m2.w, m3.x, m3.y, m3.z, m3.w};
        float musq = 0.f;
        #pragma unroll
        for (int d = 0; d < D_; ++d) musq = fmaf(mv[d], mv[d], musq);
        double l = 0.0;
        #pragma unroll
        for (int r = 0; r < RPT; ++r) {
            float uq[D_] = {R[r][0].x, R[r][0].y, R[r][0].z, R[r][0].w,
                            R[r][1].x, R[r][1].y, R[r][1].z, R[r][1].w,
                            R[r][2].x, R[r][2].y, R[r][2].z, R[r][2].w,
                            R[r][3].x, R[r][3].y, R[r][3].z, R[r][3].w};
            float dot = 0.f;
            #pragma unroll
            for (int d = 0; d < D_; ++d) dot = fmaf(uq[d], mv[d], dot);
            float d2 = fmaf(-2.f, dot, usq[r] + musq);
            l += (double)sqrtf(fmaxf(d2, 0.f));
        }
        l = wave_sum_f64(l);
        if (lane == 63) lpart[h][wv] = l;
    }
    __syncthreads();

    if (tid < H_) {
        double t = 0.0;
        #pragma unroll
        for (int w = 0; w < NW; ++w) t += lpart[tid][w];
        losses[tid] = t;
    }
    __syncthreads();
    if (tid == 0) {
        int best = 0; double bl = losses[0];
        #pragma unroll
        for (int h = 1; h < H_; ++h)
            if (losses[h] < bl) { bl = losses[h]; best = h; }
        hstar = best;
    }
    __syncthreads();
    if (tid < D_)
        out[(size_t)bo * D_ + tid] = Mu_s[hstar][tid];
}

// ================= ABLATION 1: stage only (loads + scatter + vn) ==========
__global__ __launch_bounds__(NT, 3) void abl_stage(
    const float* __restrict__ up,
    const int*   __restrict__ sidx,
    float*       __restrict__ ws)
{
    __shared__ unsigned mask[H_][MASKW];
    const int blk = blockIdx.x;
    const int p   = blk % (B_ * O_);
    int b, o; task_bo(p, b, o);
    const int tid = threadIdx.x;

    if (tid < H_ * MASKW) ((unsigned*)mask)[tid] = 0u;
    __syncthreads();

    const int* sb = sidx + (size_t)b * (S_ * O_ * H_) + o * H_;
    const bool p2 = tid < (S_ - 2 * NT);
    const int2* ps0 = (const int2*)(sb + (size_t)tid * (O_ * H_));
    const int2* ps1 = (const int2*)(sb + (size_t)(tid + NT) * (O_ * H_));
    int2 a0 = ps0[0], a1 = ps0[1], a2 = ps0[2], a3 = ps0[3], a4 = ps0[4];
    int2 b0 = ps1[0], b1 = ps1[1], b2 = ps1[2], b3 = ps1[3], b4 = ps1[4];
    int2 c0 = {0,0}, c1 = {0,0}, c2 = {0,0}, c3 = {0,0}, c4 = {0,0};
    if (p2) {
        const int2* ps2 = (const int2*)(sb + (size_t)(tid + 2 * NT) * (O_ * H_));
        c0 = ps2[0]; c1 = ps2[1]; c2 = ps2[2]; c3 = ps2[3]; c4 = ps2[4];
    }

    const float* ub = up + ((size_t)b * I_ * O_ + o) * D_;
    float4 R[RPT][4];
    #pragma unroll
    for (int r = 0; r < RPT; ++r) {
        const float4* pp = (const float4*)(ub + (size_t)(tid + r * NT) * (O_ * D_));
        R[r][0] = pp[0]; R[r][1] = pp[1]; R[r][2] = pp[2]; R[r][3] = pp[3];
    }

    {
        int v0[H_] = {a0.x, a0.y, a1.x, a1.y, a2.x, a2.y, a3.x, a3.y, a4.x, a4.y};
        #pragma unroll
        for (int h = 0; h < H_; ++h)
            atomicOr(&mask[h][v0[h] >> 5], 1u << (v0[h] & 31));
        int v1[H_] = {b0.x, b0.y, b1.x, b1.y, b2.x, b2.y, b3.x, b3.y, b4.x, b4.y};
        #pragma unroll
        for (int h = 0; h < H_; ++h)
            atomicOr(&mask[h][v1[h] >> 5], 1u << (v1[h] & 31));
        if (p2) {
            int v2[H_] = {c0.x, c0.y, c1.x, c1.y, c2.x, c2.y, c3.x, c3.y, c4.x, c4.y};
            #pragma unroll
            for (int h = 0; h < H_; ++h)
                atomicOr(&mask[h][v2[h] >> 5], 1u << (v2[h] & 31));
        }
    }

    float vn[RPT], usq[RPT];
    #pragma unroll
    for (int r = 0; r < RPT; ++r) {
        float4 q0 = R[r][0], q1 = R[r][1], q2 = R[r][2], q3 = R[r][3];
        float s = q0.x*q0.x + q0.y*q0.y + q0.z*q0.z + q0.w*q0.w
                + q1.x*q1.x + q1.y*q1.y + q1.z*q1.z + q1.w*q1.w
                + q2.x*q2.x + q2.y*q2.y + q2.z*q2.z + q2.w*q2.w
                + q3.x*q3.x + q3.y*q3.y + q3.z*q3.z + q3.w*q3.w;
        vn[r] = sqrtf(s);
        float uq[D_] = {q0.x,q0.y,q0.z,q0.w, q1.x,q1.y,q1.z,q1.w,
                        q2.x,q2.y,q2.z,q2.w, q3.x,q3.y,q3.z,q3.w};
        float t = 0.f;
        #pragma unroll
        for (int d = 0; d < D_; ++d) t = fmaf(uq[d], uq[d], t);
        usq[r] = t;
    }
    __syncthreads();
    float cs = vn[0] + vn[1] + vn[2] + usq[0] + usq[1] + usq[2]
             + (float)mask[tid % H_][tid % MASKW];
    ws[(size_t)blk * NT + tid] = cs;
}

// ================= ABLATION 2: compute only (no global loads) =============
__global__ __launch_bounds__(NT, 3) void abl_compute(float* __restrict__ ws)
{
    __shared__ unsigned                 mask[H_][MASKW];
    __shared__ __align__(16) float      hred[HH][NW][20];
    __shared__ float                    Mu_s[H_][D_];
    __shared__ double                   lpart[H_][NW];
    __shared__ double                   losses[H_];
    __shared__ int                      hstar;

    const int tid  = threadIdx.x;
    const int lane = tid & 63;
    const int wv   = tid >> 6;

    if (tid < H_ * MASKW) ((unsigned*)mask)[tid] = 0u;
    __syncthreads();
    // fabricated sparse mask (deterministic, nonzero denominators)
    atomicOr(&mask[tid % H_][(tid >> 2) % MASKW], 1u << (tid & 31));

    // fabricated register rows (no loads)
    float4 R[RPT][4];
    #pragma unroll
    for (int r = 0; r < RPT; ++r) {
        #pragma unroll
        for (int c = 0; c < 4; ++c) {
            float base = (float)((tid * 131 + r * 37 + c * 11) & 255) * 0.01f + 0.25f;
            R[r][c] = make_float4(base, base + 0.1f, base + 0.2f, base + 0.3f);
        }
    }
    float vn[RPT], usq[RPT];
    #pragma unroll
    for (int r = 0; r < RPT; ++r) {
        float4 q0 = R[r][0], q1 = R[r][1], q2 = R[r][2], q3 = R[r][3];
        float s = q0.x*q0.x + q0.y*q0.y + q0.z*q0.z + q0.w*q0.w
                + q1.x*q1.x + q1.y*q1.y + q1.z*q1.z + q1.w*q1.w
                + q2.x*q2.x + q2.y*q2.y + q2.z*q2.z + q2.w*q2.w
                + q3.x*q3.x + q3.y*q3.y + q3.z*q3.z + q3.w*q3.w;
        vn[r] = sqrtf(s);
        float uq[D_] = {q0.x,q0.y,q0.z,q0.w, q1.x,q1.y,q1.z,q1.w,
                        q2.x,q2.y,q2.z,q2.w, q3.x,q3.y,q3.z,q3.w};
        float t = 0.f;
        #pragma unroll
        for (int d = 0; d < D_; ++d) t = fmaf(uq[d], uq[d], t);
        usq[r] = t;
    }
    __syncthreads();

    const int      w0   = tid >> 5;
    const unsigned bitm = 1u << (tid & 31);
    for (int h = 0; h < HH; ++h) {
        float na[17];
        #pragma unroll
        for (int d = 0; d < 17; ++d) na[d] = 0.f;
        #pragma unroll
        for (int r = 0; r < RPT; ++r) {
            float w = vn[r];
            if (h < H_) {
                unsigned mw = mask[h][w0 + 12 * r];
                w = (mw & bitm) ? 0.f : w;
            }
            float4 q0 = R[r][0], q1 = R[r][1], q2 = R[r][2], q3 = R[r][3];
            na[ 0] = fmaf(w, q0.x, na[ 0]); na[ 1] = fmaf(w, q0.y, na[ 1]);
            na[ 2] = fmaf(w, q0.z, na[ 2]); na[ 3] = fmaf(w, q0.w, na[ 3]);
            na[ 4] = fmaf(w, q1.x, na[ 4]); na[ 5] = fmaf(w, q1.y, na[ 5]);
            na[ 6] = fmaf(w, q1.z, na[ 6]); na[ 7] = fmaf(w, q1.w, na[ 7]);
            na[ 8] = fmaf(w, q2.x, na[ 8]); na[ 9] = fmaf(w, q2.y, na[ 9]);
            na[10] = fmaf(w, q2.z, na[10]); na[11] = fmaf(w, q2.w, na[11]);
            na[12] = fmaf(w, q3.x, na[12]); na[13] = fmaf(w, q3.y, na[13]);
            na[14] = fmaf(w, q3.z, na[14]); na[15] = fmaf(w, q3.w, na[15]);
            na[16] += w;
        }
        #pragma unroll
        for (int d = 0; d < 17; ++d) na[d] = wave_sum_f32(na[d]);
        if (lane == 63) {
            *(float4*)&hred[h][wv][ 0] = make_float4(na[ 0], na[ 1], na[ 2], na[ 3]);
            *(float4*)&hred[h][wv][ 4] = make_float4(na[ 4], na[ 5], na[ 6], na[ 7]);
            *(float4*)&hred[h][wv][ 8] = make_float4(na[ 8], na[ 9], na[10], na[11]);
            *(float4*)&hred[h][wv][12] = make_float4(na[12], na[13], na[14], na[15]);
            hred[h][wv][16] = na[16];
        }
    }
    __syncthreads();

    for (int h = wv; h < H_; h += NW) {
        if (lane < D_) {
            float naj = 0.f, totj = 0.f, na16 = 0.f, tot16 = 0.f;
            #pragma unroll
            for (int w = 0; w < NW; ++w) {
                naj   += hred[h ][w][lane];
                totj  += hred[10][w][lane];
                na16  += hred[h ][w][16];
                tot16 += hred[10][w][16];
            }
            float rd = 1.f / (tot16 - na16);
            Mu_s[h][lane] = (totj - naj) * rd;
        }
    }
    __syncthreads();

    for (int h = 0; h < H_; ++h) {
        float4 m0 = *(const float4*)&Mu_s[h][0];
        float4 m1 = *(const float4*)&Mu_s[h][4];
        float4 m2 = *(const float4*)&Mu_s[h][8];
        float4 m3 = *(const float4*)&Mu_s[h][12];
        float mv[D_] = {m0.x, m0.y, m0.z, m0.w, m1.x, m1.y, m1.z, m1.w,
                        m2.x, m2.y, m2.z, m2.w, m3.x, m3.y, m3.z, m3.w};
        float musq = 0.f;
        #pragma unroll
        for (int d = 0; d < D_; ++d) musq = fmaf(mv[d], mv[d], musq);
        double l = 0.0;
        #pragma unroll
        for (int r = 0; r < RPT; ++r) {
            float uq[D_] = {R[r][0].x, R[r][0].y, R[r][0].z, R[r][0].w,
                            R[r][1].x, R[r][1].y, R[r][1].z, R[r][1].w,
                            R[r][2].x, R[r][2].y, R[r][2].z, R[r][2].w,
                            R[r][3].x, R[r][3].y, R[r][3].z, R[r][3].w};
            float dot = 0.f;
            #pragma unroll
            for (int d = 0; d < D_; ++d) dot = fmaf(uq[d], mv[d], dot);
            float d2 = fmaf(-2.f, dot, usq[r] + musq);
            l += (double)sqrtf(fmaxf(d2, 0.f));
        }
        l = wave_sum_f64(l);
        if (lane == 63) lpart[h][wv] = l;
    }
    __syncthreads();

    if (tid < H_) {
        double t = 0.0;
        #pragma unroll
        for (int w = 0; w < NW; ++w) t += lpart[tid][w];
        losses[tid] = t;
    }
    __syncthreads();
    if (tid == 0) {
        int best = 0; double bl = losses[0];
        #pragma unroll
        for (int h = 1; h < H_; ++h)
            if (losses[h] < bl) { bl = losses[h]; best = h; }
        hstar = best;
    }
    __syncthreads();
    ws[(size_t)blockIdx.x * NT + tid] = Mu_s[hstar][tid & 15];
}

// ====== ABLATION 3: skeleton (DPP/LDS/barriers, trivial bodies) ===========
__global__ __launch_bounds__(NT, 3) void abl_skel(float* __restrict__ ws)
{
    __shared__ unsigned                 mask[H_][MASKW];
    __shared__ __align__(16) float      hred[HH][NW][20];
    __shared__ float                    Mu_s[H_][D_];
    __shared__ double                   lpart[H_][NW];
    __shared__ double                   losses[H_];
    __shared__ int                      hstar;

    const int tid  = threadIdx.x;
    const int lane = tid & 63;
    const int wv   = tid >> 6;

    if (tid < H_ * MASKW) ((unsigned*)mask)[tid] = 0u;
    __syncthreads();
    atomicOr(&mask[tid % H_][(tid >> 2) % MASKW], 1u << (tid & 31));

    float vn[RPT], usq[RPT];
    #pragma unroll
    for (int r = 0; r < RPT; ++r) {
        vn[r]  = 0.5f + 0.001f * (float)((tid + r) & 63);
        usq[r] = vn[r] * 2.f;
    }
    __syncthreads();

    const int      w0   = tid >> 5;
    const unsigned bitm = 1u << (tid & 31);
    for (int h = 0; h < HH; ++h) {
        float na[17];
        #pragma unroll
        for (int d = 0; d < 17; ++d) na[d] = vn[0] + (float)(d + h);
        #pragma unroll
        for (int r = 0; r < RPT; ++r) {      // mask read kept, fma body dropped
            float w = vn[r];
            if (h < H_) {
                unsigned mw = mask[h][w0 + 12 * r];
                w = (mw & bitm) ? 0.f : w;
            }
            na[16] += w;
        }
        #pragma unroll
        for (int d = 0; d < 17; ++d) na[d] = wave_sum_f32(na[d]);
        if (lane == 63) {
            *(float4*)&hred[h][wv][ 0] = make_float4(na[ 0], na[ 1], na[ 2], na[ 3]);
            *(float4*)&hred[h][wv][ 4] = make_float4(na[ 4], na[ 5], na[ 6], na[ 7]);
            *(float4*)&hred[h][wv][ 8] = make_float4(na[ 8], na[ 9], na[10], na[11]);
            *(float4*)&hred[h][wv][12] = make_float4(na[12], na[13], na[14], na[15]);
            hred[h][wv][16] = na[16];
        }
    }
    __syncthreads();

    for (int h = wv; h < H_; h += NW) {
        if (lane < D_) {
            float naj = 0.f, totj = 0.f, na16 = 0.f, tot16 = 0.f;
            #pragma unroll
            for (int w = 0; w < NW; ++w) {
                naj   += hred[h ][w][lane];
                totj  += hred[10][w][lane];
                na16  += hred[h ][w][16];
                tot16 += hred[10][w][16];
            }
            float rd = 1.f / (tot16 - na16);
            Mu_s[h][lane] = (totj - naj) * rd;
        }
    }
    __syncthreads();

    for (int h = 0; h < H_; ++h) {
        float4 m0 = *(const float4*)&Mu_s[h][0];
        float4 m1 = *(const float4*)&Mu_s[h][4];
        float4 m2 = *(const float4*)&Mu_s[h][8];
        float4 m3 = *(const float4*)&Mu_s[h][12];
        float musq = m0.x*m0.x + m1.x*m1.x + m2.x*m2.x + m3.x*m3.x;
        double l = 0.0;
        #pragma unroll
        for (int r = 0; r < RPT; ++r) {      // dot body dropped
            float d2 = fmaf(-2.f, musq, usq[r] + musq);
            l += (double)sqrtf(fmaxf(d2, 0.f));
        }
        l = wave_sum_f64(l);
        if (lane == 63) lpart[h][wv] = l;
    }
    __syncthreads();

    if (tid < H_) {
        double t = 0.0;
        #pragma unroll
        for (int w = 0; w < NW; ++w) t += lpart[tid][w];
        losses[tid] = t;
    }
    __syncthreads();
    if (tid == 0) {
        int best = 0; double bl = losses[0];
        #pragma unroll
        for (int h = 1; h < H_; ++h)
            if (losses[h] < bl) { bl = losses[h]; best = h; }
        hstar = best;
    }
    __syncthreads();
    ws[(size_t)blockIdx.x * NT + tid] = Mu_s[hstar][tid & 15];
}

extern "C" void kernel_launch(void* const* d_in, const int* in_sizes, int n_in,
                              void* d_out, int out_size, void* d_ws, size_t ws_size,
                              hipStream_t stream) {
    const float* up   = (const float*)d_in[0];
    const int*   sidx = (const int*)d_in[1];
    float*       out  = (float*)d_out;
    float*       wsf  = (float*)d_ws;
    // real (correct) kernel first
    ransac_kernel<<<B_ * O_, NT, 0, stream>>>(up, sidx, out);
    // diagnostic ablations (ws-only; 8x grid to rank above fill dispatches)
    abl_stage  <<<ABLG, NT, 0, stream>>>(up, sidx, wsf);
    abl_compute<<<ABLG, NT, 0, stream>>>(wsf);
    abl_skel   <<<ABLG, NT, 0, stream>>>(wsf);
}

// Round 9
// 106.722 us; speedup vs baseline: 3.6472x; 3.6472x over previous
//
#include <hip/hip_runtime.h>
#include <math.h>

// RansacRouting: B=32, I=1152, O=10, D=16, H=10, S=922
// Round 9: ablation (R8) showed compute=19us per-320-packed (VALUBusy 73%),
// stage<5.5, skeleton<5.5. Dominant term: DPP reduction, which scales with
// WAVE COUNT (NW x 11h x 17 x 12 ops). Fix: fat threads (9 rows/thread,
// single-wave blocks) -> 2 waves/task of reduction instead of 6, and
// 640 uniform blocks kill the 2T tail (44us = 2x22, occ 13%).
// Pipeline (kernel-boundary sync only; R5 lesson):
//   K0 masks: R7's verified coalesced mask build        (256 x 256)
//   K1 scan : masked scan halves -> hredG[640][11][20]  (640 x 64, rpt=9)
//   K2 loss : comb hred -> Mu -> loss partials -> lossG (640 x 64, rpt=9)
//   K3 pick : argmin + Mu[h*] recompute -> out          (320 x 64)

#define B_    32
#define I_    1152
#define O_    10
#define D_    16
#define H_    10
#define S_    922
#define MASKW 36      // 1152/32
#define HH    11      // 10 hypotheses + 1 "all rows" (tot)
#define NPAIR 320
#define HROWS 576     // rows per half
#define RPT   9       // rows per thread (64 thr x 9 = 576)
#define K0NT  256
#define SCH   116     // ceil(922/8) s per K0 slot
#define MWORDS (O_ * H_ * MASKW)   // 3600 words per (slot,b)
#define HSTRIDE 20    // float stride per h in hredG (16B-aligned float4s)

#define WS_HRED_OFF 0x500000u   // float  [640][11][20]  (563 KB)
#define WS_LOSS_OFF 0x600000u   // double [640][10]      (51 KB)

// ---- wave64 sum via DPP (VALU pipe, no LDS) -- result valid in lane 63 ----
template <int CTRL, int ROWM>
static __device__ __forceinline__ float dpp_f(float v) {
    return __int_as_float(__builtin_amdgcn_update_dpp(
        0, __float_as_int(v), CTRL, ROWM, 0xf, true));
}
static __device__ __forceinline__ float wave_sum_f32(float v) {
    v += dpp_f<0x111, 0xf>(v);   // row_shr:1
    v += dpp_f<0x112, 0xf>(v);   // row_shr:2
    v += dpp_f<0x114, 0xf>(v);   // row_shr:4
    v += dpp_f<0x118, 0xf>(v);   // row_shr:8
    v += dpp_f<0x142, 0xa>(v);   // row_bcast15 -> rows 1,3
    v += dpp_f<0x143, 0xc>(v);   // row_bcast31 -> rows 2,3
    return v;                    // lane 63 holds the total
}
template <int CTRL, int ROWM>
static __device__ __forceinline__ double dpp_d(double v) {
    long long x = __double_as_longlong(v);
    int lo = (int)(unsigned)(x & 0xffffffffLL);
    int hi = (int)(x >> 32);
    lo = __builtin_amdgcn_update_dpp(0, lo, CTRL, ROWM, 0xf, true);
    hi = __builtin_amdgcn_update_dpp(0, hi, CTRL, ROWM, 0xf, true);
    return __longlong_as_double((long long)(unsigned)lo | ((long long)hi << 32));
}
static __device__ __forceinline__ double wave_sum_f64(double v) {
    v += dpp_d<0x111, 0xf>(v);
    v += dpp_d<0x112, 0xf>(v);
    v += dpp_d<0x114, 0xf>(v);
    v += dpp_d<0x118, 0xf>(v);
    v += dpp_d<0x142, 0xa>(v);
    v += dpp_d<0x143, 0xc>(v);
    return v;
}

// task index p -> (b, o): XCD-aware (b&7 == p&7); all K grids keep blk&7==p&7
static __device__ __forceinline__ void task_bo(int p, int& b, int& o) {
    int xcd = p & 7, g = p >> 3;
    int gg = g / O_;
    b = xcd + 8 * gg;
    o = g - O_ * gg;
}

// ---------------- K0: coalesced mask build (verified R7) ------------------
__global__ __launch_bounds__(K0NT, 2) void ransac_masks(
    const int*  __restrict__ sidx,     // [B,S,O,H]
    unsigned*   __restrict__ maskG)    // [8][32][10][10][36]
{
    __shared__ unsigned lm[MWORDS];    // 14400 B
    const int blk = blockIdx.x;
    const int b = blk & 31, k = blk >> 5;
    const int tid = threadIdx.x;

    for (int t = tid; t < MWORDS; t += K0NT) lm[t] = 0u;
    __syncthreads();

    const int s0  = k * SCH;
    const int cnt = min(S_ - s0, SCH);
    const int n4  = cnt * 25;                  // cnt*100 ints / 4
    const int4* base = (const int4*)(sidx + (size_t)b * (S_ * O_ * H_)
                                          + (size_t)s0 * (O_ * H_));
    for (int j4 = tid; j4 < n4; j4 += K0NT) {
        int4 v = base[j4];
        int vv[4] = {v.x, v.y, v.z, v.w};
        int j = j4 * 4;                        // flat int index: s*100+o*10+h
        #pragma unroll
        for (int e = 0; e < 4; ++e) {
            int jj  = j + e;
            int rem = jj % 100;                // o*10 + h
            int o   = rem / 10;
            int h   = rem - 10 * o;
            int val = vv[e];
            atomicOr(&lm[(o * H_ + h) * MASKW + (val >> 5)], 1u << (val & 31));
        }
    }
    __syncthreads();

    unsigned* dst = maskG + (size_t)blk * MWORDS;
    for (int t = tid; t < MWORDS; t += K0NT) dst[t] = lm[t];
}

// ---------------- K1: masked scan (half-task, 1 wave, rpt=9) --------------
__global__ __launch_bounds__(64, 1) void ransac_scan(
    const float*    __restrict__ up,      // [B,I,O,D]
    const unsigned* __restrict__ maskG,   // [8][32][10][10][36]
    float*          __restrict__ hredG)   // [640][11][20]
{
    __shared__ unsigned mask[H_][HROWS / 32];   // [10][18], 720 B

    const int blk  = blockIdx.x;               // [half*320 + p]
    const int half = (blk >= NPAIR) ? 1 : 0;
    const int p    = blk - NPAIR * half;
    int b, o; task_bo(p, b, o);
    const int r0  = half * HROWS;
    const int tid = threadIdx.x;               // 0..63

    // (1) mask slot loads + OR -> LDS (own 18-word half range, 8 slots)
    for (int w = tid; w < H_ * (HROWS / 32); w += 64) {
        int h  = w / 18;
        int lw = w - 18 * h;
        unsigned m = 0u;
        #pragma unroll
        for (int k = 0; k < 8; ++k)
            m |= maskG[(size_t)(k * 32 + b) * MWORDS
                       + (o * H_ + h) * MASKW + half * 18 + lw];
        mask[h][lw] = m;
    }

    // (2) u loads -- own 9 rows (rows r0 + tid + 64r)
    const float* ub = up + ((size_t)b * I_ * O_ + o) * D_;
    float4 R[RPT][4];
    #pragma unroll
    for (int r = 0; r < RPT; ++r) {
        const float4* pr = (const float4*)(ub + (size_t)(r0 + tid + 64 * r) * (O_ * D_));
        R[r][0] = pr[0]; R[r][1] = pr[1]; R[r][2] = pr[2]; R[r][3] = pr[3];
    }

    // (3) vn per row
    float vn[RPT];
    #pragma unroll
    for (int r = 0; r < RPT; ++r) {
        float4 q0 = R[r][0], q1 = R[r][1], q2 = R[r][2], q3 = R[r][3];
        float s = q0.x*q0.x + q0.y*q0.y + q0.z*q0.z + q0.w*q0.w
                + q1.x*q1.x + q1.y*q1.y + q1.z*q1.z + q1.w*q1.w
                + q2.x*q2.x + q2.y*q2.y + q2.z*q2.z + q2.w*q2.w
                + q3.x*q3.x + q3.y*q3.y + q3.z*q3.z + q3.w*q3.w;
        vn[r] = sqrtf(s);
    }
    __syncthreads();   // mask LDS visible

    // (4) masked scan: h<10 -> complement partial; h==10 -> tot
    const int      w0   = tid >> 5;        // local row j = tid+64r -> word w0+2r
    const unsigned bitm = 1u << (tid & 31);
    for (int h = 0; h < HH; ++h) {
        float na[17];
        #pragma unroll
        for (int d = 0; d < 17; ++d) na[d] = 0.f;
        #pragma unroll
        for (int r = 0; r < RPT; ++r) {
            float w = vn[r];
            if (h < H_) {
                unsigned mw = mask[h][w0 + 2 * r];
                w = (mw & bitm) ? 0.f : w;     // sampled row -> excluded
            }
            float4 q0 = R[r][0], q1 = R[r][1], q2 = R[r][2], q3 = R[r][3];
            na[ 0] = fmaf(w, q0.x, na[ 0]); na[ 1] = fmaf(w, q0.y, na[ 1]);
            na[ 2] = fmaf(w, q0.z, na[ 2]); na[ 3] = fmaf(w, q0.w, na[ 3]);
            na[ 4] = fmaf(w, q1.x, na[ 4]); na[ 5] = fmaf(w, q1.y, na[ 5]);
            na[ 6] = fmaf(w, q1.z, na[ 6]); na[ 7] = fmaf(w, q1.w, na[ 7]);
            na[ 8] = fmaf(w, q2.x, na[ 8]); na[ 9] = fmaf(w, q2.y, na[ 9]);
            na[10] = fmaf(w, q2.z, na[10]); na[11] = fmaf(w, q2.w, na[11]);
            na[12] = fmaf(w, q3.x, na[12]); na[13] = fmaf(w, q3.y, na[13]);
            na[14] = fmaf(w, q3.z, na[14]); na[15] = fmaf(w, q3.w, na[15]);
            na[16] += w;
        }
        #pragma unroll
        for (int d = 0; d < 17; ++d) na[d] = wave_sum_f32(na[d]);
        if (tid == 63) {                       // single wave: partial == block sum
            float* dst = hredG + (size_t)blk * (HH * HSTRIDE) + h * HSTRIDE;
            *(float4*)(dst +  0) = make_float4(na[ 0], na[ 1], na[ 2], na[ 3]);
            *(float4*)(dst +  4) = make_float4(na[ 4], na[ 5], na[ 6], na[ 7]);
            *(float4*)(dst +  8) = make_float4(na[ 8], na[ 9], na[10], na[11]);
            *(float4*)(dst + 12) = make_float4(na[12], na[13], na[14], na[15]);
            dst[16] = na[16];
        }
    }
}

// ---------------- K2: Mu + loss partials (half-task, 1 wave, rpt=9) -------
__global__ __launch_bounds__(64, 1) void ransac_loss(
    const float* __restrict__ up,       // [B,I,O,D]
    const float* __restrict__ hredG,    // [640][11][20]
    double*      __restrict__ lossG)    // [640][10]
{
    __shared__ float               comb[HH][17];   // 748 B
    __shared__ __align__(16) float Mu_s[H_][D_];   // 640 B

    const int blk  = blockIdx.x;
    const int half = (blk >= NPAIR) ? 1 : 0;
    const int p    = blk - NPAIR * half;
    int b, o; task_bo(p, b, o);
    const int r0  = half * HROWS;
    const int tid = threadIdx.x;

    // (1) u loads -- own 9 rows
    const float* ub = up + ((size_t)b * I_ * O_ + o) * D_;
    float4 R[RPT][4];
    #pragma unroll
    for (int r = 0; r < RPT; ++r) {
        const float4* pr = (const float4*)(ub + (size_t)(r0 + tid + 64 * r) * (O_ * D_));
        R[r][0] = pr[0]; R[r][1] = pr[1]; R[r][2] = pr[2]; R[r][3] = pr[3];
    }

    // (2) combined hred (fixed order half0+half1 -> identical in both halves)
    for (int t = tid; t < HH * 17; t += 64) {
        int h = t / 17, d = t - 17 * h;
        comb[h][d] = hredG[(size_t)p            * (HH * HSTRIDE) + h * HSTRIDE + d]
                   + hredG[(size_t)(NPAIR + p) * (HH * HSTRIDE) + h * HSTRIDE + d];
    }
    __syncthreads();
    for (int t = tid; t < H_ * D_; t += 64) {
        int h = t >> 4, d = t & 15;
        float rd = 1.f / (comb[10][16] - comb[h][16]);
        Mu_s[h][d] = (comb[10][d] - comb[h][d]) * rd;
    }
    __syncthreads();   // Mu ready

    // (3) usq per row
    float usq[RPT];
    #pragma unroll
    for (int r = 0; r < RPT; ++r) {
        float4 q0 = R[r][0], q1 = R[r][1], q2 = R[r][2], q3 = R[r][3];
        float uq[D_] = {q0.x,q0.y,q0.z,q0.w, q1.x,q1.y,q1.z,q1.w,
                        q2.x,q2.y,q2.z,q2.w, q3.x,q3.y,q3.z,q3.w};
        float t = 0.f;
        #pragma unroll
        for (int d = 0; d < D_; ++d) t = fmaf(uq[d], uq[d], t);
        usq[r] = t;
    }

    // (4) loss partials over own rows (h-outer; Mu broadcast from LDS)
    for (int h = 0; h < H_; ++h) {
        float4 m0 = *(const float4*)&Mu_s[h][0];
        float4 m1 = *(const float4*)&Mu_s[h][4];
        float4 m2 = *(const float4*)&Mu_s[h][8];
        float4 m3 = *(const float4*)&Mu_s[h][12];
        float mv[D_] = {m0.x, m0.y, m0.z, m0.w, m1.x, m1.y, m1.z, m1.w,
                        m2.x, m2.y, m2.z, m2.w, m3.x, m3.y, m3.z, m3.w};
        float musq = 0.f;
        #pragma unroll
        for (int d = 0; d < D_; ++d) musq = fmaf(mv[d], mv[d], musq);
        double l = 0.0;
        #pragma unroll
        for (int r = 0; r < RPT; ++r) {
            float uq[D_] = {R[r][0].x, R[r][0].y, R[r][0].z, R[r][0].w,
                            R[r][1].x, R[r][1].y, R[r][1].z, R[r][1].w,
                            R[r][2].x, R[r][2].y, R[r][2].z, R[r][2].w,
                            R[r][3].x, R[r][3].y, R[r][3].z, R[r][3].w};
            float dot = 0.f;
            #pragma unroll
            for (int d = 0; d < D_; ++d) dot = fmaf(uq[d], mv[d], dot);
            float d2 = fmaf(-2.f, dot, usq[r] + musq);
            l += (double)sqrtf(fmaxf(d2, 0.f));
        }
        l = wave_sum_f64(l);
        if (tid == 63) lossG[(size_t)blk * H_ + h] = l;
    }
}

// ---------------- K3: argmin + Mu[h*] -> out ------------------------------
__global__ __launch_bounds__(64, 8) void ransac_pick(
    const double* __restrict__ lossG,   // [640][10]
    const float*  __restrict__ hredG,   // [640][11][20]
    float*        __restrict__ out)     // [B,O,D]
{
    __shared__ double lc[H_];
    __shared__ int    hstar;
    const int p = blockIdx.x;
    int b, o; task_bo(p, b, o);
    const int tid = threadIdx.x;

    if (tid < H_)
        lc[tid] = lossG[(size_t)p * H_ + tid]
                + lossG[(size_t)(NPAIR + p) * H_ + tid];
    __syncthreads();
    if (tid == 0) {
        int best = 0; double bl = lc[0];
        #pragma unroll
        for (int h = 1; h < H_; ++h)
            if (lc[h] < bl) { bl = lc[h]; best = h; }
        hstar = best;
    }
    __syncthreads();
    if (tid < D_) {
        const float* s0 = hredG + (size_t)p            * (HH * HSTRIDE);
        const float* s1 = hredG + (size_t)(NPAIR + p) * (HH * HSTRIDE);
        int hs = hstar;
        float c10d = s0[10 * HSTRIDE + tid] + s1[10 * HSTRIDE + tid];
        float chd  = s0[hs * HSTRIDE + tid] + s1[hs * HSTRIDE + tid];
        float c10s = s0[10 * HSTRIDE + 16]  + s1[10 * HSTRIDE + 16];
        float chs  = s0[hs * HSTRIDE + 16]  + s1[hs * HSTRIDE + 16];
        float rd = 1.f / (c10s - chs);
        out[((size_t)b * O_ + o) * D_ + tid] = (c10d - chd) * rd;
    }
}

extern "C" void kernel_launch(void* const* d_in, const int* in_sizes, int n_in,
                              void* d_out, int out_size, void* d_ws, size_t ws_size,
                              hipStream_t stream) {
    const float* up   = (const float*)d_in[0];
    const int*   sidx = (const int*)d_in[1];
    float*       out  = (float*)d_out;
    unsigned* maskG = (unsigned*)d_ws;                        // 4.61 MB @ 0
    float*    hredG = (float*)((char*)d_ws + WS_HRED_OFF);    // 563 KB
    double*   lossG = (double*)((char*)d_ws + WS_LOSS_OFF);   // 51 KB
    ransac_masks<<<8 * B_,     K0NT, 0, stream>>>(sidx, maskG);
    ransac_scan <<<2 * NPAIR,  64,   0, stream>>>(up, maskG, hredG);
    ransac_loss <<<2 * NPAIR,  64,   0, stream>>>(up, hredG, lossG);
    ransac_pick <<<NPAIR,      64,   0, stream>>>(lossG, hredG, out);
}